// Round 3
// baseline (48.602 us; speedup 1.0000x reference)
//
#include <hip/hip_runtime.h>

#define NS 384
#define NT 384
#define D  256
#define NBLK 768            // block = (t, half-of-i); 768 = 3 * 256 CUs exactly
#define GRP_PER_WAVE 12     // 4 waves * 12 groups = 48 groups = half of 96
#define MAGIC 0x5CA1AB1Eu
#define SPIN_MAX (1 << 24)

// reduce within each 32-lane half (offsets never cross the half boundary)
__device__ __forceinline__ float half_sum32(float v) {
#pragma unroll
    for (int off = 16; off; off >>= 1) v += __shfl_xor(v, off, 64);
    return v;
}
__device__ __forceinline__ float wave_sum64(float v) {
#pragma unroll
    for (int off = 32; off; off >>= 1) v += __shfl_xor(v, off, 64);
    return v;
}

// Single fused kernel. loss_t = ||S_t||^2 - 2 * sum_g ||S_g||^2.
// Block b: t = b>>1, half = b&1 (192 i's = 48 groups).
// half==0: producer (publishes its half-S vector + g-partial, sets flag1[t]).
// half==1: consumer (waits flag1[t], computes loss_t, sets flag2[t]).
// Block NBLK-1: additionally consumes all flag2 and writes the final scalar.
// Flags are consumed via atomicCAS(MAGIC->0): self-resetting, no memset node,
// deterministic (fixed-order reductions, no float atomics).
__global__ __launch_bounds__(256) void fused_kernel(
        const float* __restrict__ src, const float* __restrict__ trgt,
        float* __restrict__ Svec0,      // [NT][D]
        float* __restrict__ g0,         // [NT]
        float* __restrict__ lossArr,    // [NT]
        unsigned* __restrict__ flag1,   // [NT]
        unsigned* __restrict__ flag2,   // [NT]
        float* __restrict__ out) {
    const int b    = blockIdx.x;
    const int t    = b >> 1;
    const int half = b & 1;
    const int wave = threadIdx.x >> 6;
    const int lane = threadIdx.x & 63;
    const int hl   = lane & 31;   // lane within half: owns dims [8*hl, 8*hl+8)
    const int hi   = lane >> 5;   // 0 -> even i, 1 -> odd i

    const float4* src4 = (const float4*)src;
    const float4* t4   = (const float4*)(trgt + (size_t)t * D);
    const float4  tv0  = t4[2*hl];
    const float4  tv1  = t4[2*hl + 1];

    float4 Sf0 = {0,0,0,0}, Sf1 = {0,0,0,0};
    float  gacc = 0.f;

    const int g0i = half * 48 + wave * GRP_PER_WAVE;
#pragma unroll 2
    for (int g = g0i; g < g0i + GRP_PER_WAVE; ++g) {
        float4 Sg0 = {0,0,0,0}, Sg1 = {0,0,0,0};
#pragma unroll
        for (int p = 0; p < 2; ++p) {
            const int i = 4*g + 2*p + hi;
            const float4 sv0 = src4[i*64 + 2*hl];
            const float4 sv1 = src4[i*64 + 2*hl + 1];
            float4 d0, d1;
            d0.x = tv0.x - sv0.x; d0.y = tv0.y - sv0.y;
            d0.z = tv0.z - sv0.z; d0.w = tv0.w - sv0.w;
            d1.x = tv1.x - sv1.x; d1.y = tv1.y - sv1.y;
            d1.z = tv1.z - sv1.z; d1.w = tv1.w - sv1.w;
            float ss = d0.x*d0.x + d0.y*d0.y + d0.z*d0.z + d0.w*d0.w
                     + d1.x*d1.x + d1.y*d1.y + d1.z*d1.z + d1.w*d1.w;
            ss = half_sum32(ss);
            const float rn = rsqrtf(ss);
            Sg0.x += d0.x*rn; Sg0.y += d0.y*rn; Sg0.z += d0.z*rn; Sg0.w += d0.w*rn;
            Sg1.x += d1.x*rn; Sg1.y += d1.y*rn; Sg1.z += d1.z*rn; Sg1.w += d1.w*rn;
        }
        Sg0.x += __shfl_xor(Sg0.x, 32, 64); Sg0.y += __shfl_xor(Sg0.y, 32, 64);
        Sg0.z += __shfl_xor(Sg0.z, 32, 64); Sg0.w += __shfl_xor(Sg0.w, 32, 64);
        Sg1.x += __shfl_xor(Sg1.x, 32, 64); Sg1.y += __shfl_xor(Sg1.y, 32, 64);
        Sg1.z += __shfl_xor(Sg1.z, 32, 64); Sg1.w += __shfl_xor(Sg1.w, 32, 64);
        gacc += Sg0.x*Sg0.x + Sg0.y*Sg0.y + Sg0.z*Sg0.z + Sg0.w*Sg0.w
              + Sg1.x*Sg1.x + Sg1.y*Sg1.y + Sg1.z*Sg1.z + Sg1.w*Sg1.w;
        Sf0.x += Sg0.x; Sf0.y += Sg0.y; Sf0.z += Sg0.z; Sf0.w += Sg0.w;
        Sf1.x += Sg1.x; Sf1.y += Sg1.y; Sf1.z += Sg1.z; Sf1.w += Sg1.w;
    }

    __shared__ float sS[4][D];
    __shared__ float sG[4];
    __shared__ float sR[4];
    if (hi == 0) {
        *(float4*)&sS[wave][8*hl]     = Sf0;
        *(float4*)&sS[wave][8*hl + 4] = Sf1;
    }
    const float gw = wave_sum64(gacc) * 0.5f;
    if (lane == 0) sG[wave] = gw;
    __syncthreads();

    const int tid = threadIdx.x;
    const float s_local = sS[0][tid] + sS[1][tid] + sS[2][tid] + sS[3][tid];
    const float g_local = sG[0] + sG[1] + sG[2] + sG[3];

    if (half == 0) {
        // ---- producer: publish half-S and g-partial, release flag1[t] ----
        Svec0[t * D + tid] = s_local;
        if (tid == 0) g0[t] = g_local;
        __syncthreads();                 // all stores issued+drained (vmcnt 0)
        if (tid == 0) {
            __threadfence();             // device-scope release (wb this XCD L2)
            atomicExch(&flag1[t], MAGIC);
        }
    } else {
        // ---- consumer: acquire partner's half, compute loss_t ----
        if (tid == 0) {
            int spins = 0;
            while (atomicCAS(&flag1[t], MAGIC, 0u) != MAGIC) {
                if (++spins > SPIN_MAX) break;       // fail loud, never hang
                __builtin_amdgcn_s_sleep(2);
            }
            __threadfence();             // device-scope acquire (inv L1/L2)
        }
        __syncthreads();
        const float s_tot = s_local + Svec0[t * D + tid];
        const float v = wave_sum64(s_tot * s_tot);
        if (lane == 0) sR[wave] = v;
        __syncthreads();
        if (tid == 0) {
            const float acc = sR[0] + sR[1] + sR[2] + sR[3];
            lossArr[t] = acc - 2.f * (g0[t] + g_local);
            __threadfence();
            atomicExch(&flag2[t], MAGIC);
        }
    }

    if (b == NBLK - 1) {
        // ---- root: consume all per-t flags, fixed-order final reduction ----
        __syncthreads();
        for (int k = tid; k < NT; k += 256) {
            int spins = 0;
            while (atomicCAS(&flag2[k], MAGIC, 0u) != MAGIC) {
                if (++spins > SPIN_MAX) break;
                __builtin_amdgcn_s_sleep(2);
            }
        }
        __threadfence();
        float vsum = 0.f;
        for (int k = tid; k < NT; k += 256) vsum += lossArr[k];
        const float w = wave_sum64(vsum);
        __shared__ float sF[4];
        if (lane == 0) sF[wave] = w;
        __syncthreads();
        if (tid == 0) {
            const double tot = (double)sF[0] + (double)sF[1]
                             + (double)sF[2] + (double)sF[3];
            out[0] = (float)(tot / ((double)NS * (double)NS * (double)NT));
        }
    }
}

extern "C" void kernel_launch(void* const* d_in, const int* in_sizes, int n_in,
                              void* d_out, int out_size, void* d_ws, size_t ws_size,
                              hipStream_t stream) {
    const float* src  = (const float*)d_in[0];   // src_feats  [384, 256] f32
    const float* trgt = (const float*)d_in[1];   // trgt_feats [384, 256] f32

    float*    Svec0  = (float*)d_ws;                       // [384*256]
    float*    g0     = Svec0 + (size_t)NT * D;             // [384]
    float*    lossA  = g0 + NT;                            // [384]
    unsigned* flag1  = (unsigned*)(lossA + NT);            // [384]
    unsigned* flag2  = flag1 + NT;                         // [384]
    float*    out    = (float*)d_out;

    fused_kernel<<<NBLK, 256, 0, stream>>>(src, trgt, Svec0, g0, lossA,
                                           flag1, flag2, out);
}

// Round 4
// 23.685 us; speedup vs baseline: 2.0520x; 2.0520x over previous
//
#include <hip/hip_runtime.h>

#define NS 384
#define NT 384
#define D  256
#define NSLICE 8                      // i-range slices per target
#define GRP_SLICE 12                  // 96 groups / NSLICE
#define K1_BLOCKS ((NT / 2) * NSLICE) // 1536: block = (t-pair, slice)
#define K2_TPB 4
#define K2_BLOCKS (NT / K2_TPB)       // 96

// reduce within each 32-lane half (offsets never cross the half boundary)
__device__ __forceinline__ float half_sum32(float v) {
#pragma unroll
    for (int off = 16; off; off >>= 1) v += __shfl_xor(v, off, 64);
    return v;
}
__device__ __forceinline__ float wave_sum64(float v) {
#pragma unroll
    for (int off = 32; off; off >>= 1) v += __shfl_xor(v, off, 64);
    return v;
}

// K1: block b = (tp, slice) handles targets t0=2tp, t1=2tp+1 over 12 groups
// (48 i's). One src load feeds two independent norm chains (ILP x2, L2
// traffic /2). Lane owns 8 dims; lanes 0-31 do even i, 32-63 odd i.
// Writes S-slice vectors [t][slice][256] and g-partials [t][slice].
__global__ __launch_bounds__(256) void k1_slices(
        const float* __restrict__ src, const float* __restrict__ trgt,
        float* __restrict__ Svec, float* __restrict__ gpart,
        unsigned long long* __restrict__ llsum, unsigned* __restrict__ cnt) {
    const int b     = blockIdx.x;
    const int tp    = b >> 3;
    const int slice = b & 7;
    const int t0    = 2 * tp;
    const int t1    = 2 * tp + 1;
    const int wave  = threadIdx.x >> 6;
    const int lane  = threadIdx.x & 63;
    const int hl    = lane & 31;      // owns dims [8*hl, 8*hl+8)
    const int hi    = lane >> 5;      // 0 -> even i, 1 -> odd i

    if (b == 0 && threadIdx.x == 0) { *llsum = 0ull; *cnt = 0u; }  // reset accumulators for K2

    const float4* src4 = (const float4*)src;
    const float4* t4A  = (const float4*)(trgt + (size_t)t0 * D);
    const float4* t4B  = (const float4*)(trgt + (size_t)t1 * D);
    const float4 tvA0 = t4A[2*hl], tvA1 = t4A[2*hl + 1];
    const float4 tvB0 = t4B[2*hl], tvB1 = t4B[2*hl + 1];

    float4 SfA0 = {0,0,0,0}, SfA1 = {0,0,0,0};
    float4 SfB0 = {0,0,0,0}, SfB1 = {0,0,0,0};
    float  gaccA = 0.f, gaccB = 0.f;

    const int gbeg = slice * GRP_SLICE + wave * 3;
    for (int g = gbeg; g < gbeg + 3; ++g) {
        float4 SgA0 = {0,0,0,0}, SgA1 = {0,0,0,0};
        float4 SgB0 = {0,0,0,0}, SgB1 = {0,0,0,0};
#pragma unroll
        for (int p = 0; p < 2; ++p) {
            const int i = 4*g + 2*p + hi;
            const float4 sv0 = src4[i*64 + 2*hl];
            const float4 sv1 = src4[i*64 + 2*hl + 1];
            float4 a0, a1, b0, b1;
            a0.x = tvA0.x - sv0.x; a0.y = tvA0.y - sv0.y;
            a0.z = tvA0.z - sv0.z; a0.w = tvA0.w - sv0.w;
            a1.x = tvA1.x - sv1.x; a1.y = tvA1.y - sv1.y;
            a1.z = tvA1.z - sv1.z; a1.w = tvA1.w - sv1.w;
            b0.x = tvB0.x - sv0.x; b0.y = tvB0.y - sv0.y;
            b0.z = tvB0.z - sv0.z; b0.w = tvB0.w - sv0.w;
            b1.x = tvB1.x - sv1.x; b1.y = tvB1.y - sv1.y;
            b1.z = tvB1.z - sv1.z; b1.w = tvB1.w - sv1.w;
            float ssA = a0.x*a0.x + a0.y*a0.y + a0.z*a0.z + a0.w*a0.w
                      + a1.x*a1.x + a1.y*a1.y + a1.z*a1.z + a1.w*a1.w;
            float ssB = b0.x*b0.x + b0.y*b0.y + b0.z*b0.z + b0.w*b0.w
                      + b1.x*b1.x + b1.y*b1.y + b1.z*b1.z + b1.w*b1.w;
            ssA = half_sum32(ssA);            // two independent chains
            ssB = half_sum32(ssB);            // interleave in the ds pipe
            const float rnA = rsqrtf(ssA);    // norms ~22; EPS never binds
            const float rnB = rsqrtf(ssB);
            SgA0.x += a0.x*rnA; SgA0.y += a0.y*rnA; SgA0.z += a0.z*rnA; SgA0.w += a0.w*rnA;
            SgA1.x += a1.x*rnA; SgA1.y += a1.y*rnA; SgA1.z += a1.z*rnA; SgA1.w += a1.w*rnA;
            SgB0.x += b0.x*rnB; SgB0.y += b0.y*rnB; SgB0.z += b0.z*rnB; SgB0.w += b0.w*rnB;
            SgB1.x += b1.x*rnB; SgB1.y += b1.y*rnB; SgB1.z += b1.z*rnB; SgB1.w += b1.w*rnB;
        }
        // combine even/odd halves -> full S_g (mirror lanes own same dims)
        SgA0.x += __shfl_xor(SgA0.x, 32, 64); SgA0.y += __shfl_xor(SgA0.y, 32, 64);
        SgA0.z += __shfl_xor(SgA0.z, 32, 64); SgA0.w += __shfl_xor(SgA0.w, 32, 64);
        SgA1.x += __shfl_xor(SgA1.x, 32, 64); SgA1.y += __shfl_xor(SgA1.y, 32, 64);
        SgA1.z += __shfl_xor(SgA1.z, 32, 64); SgA1.w += __shfl_xor(SgA1.w, 32, 64);
        SgB0.x += __shfl_xor(SgB0.x, 32, 64); SgB0.y += __shfl_xor(SgB0.y, 32, 64);
        SgB0.z += __shfl_xor(SgB0.z, 32, 64); SgB0.w += __shfl_xor(SgB0.w, 32, 64);
        SgB1.x += __shfl_xor(SgB1.x, 32, 64); SgB1.y += __shfl_xor(SgB1.y, 32, 64);
        SgB1.z += __shfl_xor(SgB1.z, 32, 64); SgB1.w += __shfl_xor(SgB1.w, 32, 64);
        gaccA += SgA0.x*SgA0.x + SgA0.y*SgA0.y + SgA0.z*SgA0.z + SgA0.w*SgA0.w
               + SgA1.x*SgA1.x + SgA1.y*SgA1.y + SgA1.z*SgA1.z + SgA1.w*SgA1.w;
        gaccB += SgB0.x*SgB0.x + SgB0.y*SgB0.y + SgB0.z*SgB0.z + SgB0.w*SgB0.w
               + SgB1.x*SgB1.x + SgB1.y*SgB1.y + SgB1.z*SgB1.z + SgB1.w*SgB1.w;
        SfA0.x += SgA0.x; SfA0.y += SgA0.y; SfA0.z += SgA0.z; SfA0.w += SgA0.w;
        SfA1.x += SgA1.x; SfA1.y += SgA1.y; SfA1.z += SgA1.z; SfA1.w += SgA1.w;
        SfB0.x += SgB0.x; SfB0.y += SgB0.y; SfB0.z += SgB0.z; SfB0.w += SgB0.w;
        SfB1.x += SgB1.x; SfB1.y += SgB1.y; SfB1.z += SgB1.z; SfB1.w += SgB1.w;
    }

    __shared__ float sSA[4][D], sSB[4][D];
    __shared__ float sGA[4], sGB[4];
    if (hi == 0) {   // lanes 0..31 hold full (even+odd) group sums for their dims
        *(float4*)&sSA[wave][8*hl]     = SfA0;
        *(float4*)&sSA[wave][8*hl + 4] = SfA1;
        *(float4*)&sSB[wave][8*hl]     = SfB0;
        *(float4*)&sSB[wave][8*hl + 4] = SfB1;
    }
    const float gwA = wave_sum64(gaccA) * 0.5f;  // dims double-counted across halves
    const float gwB = wave_sum64(gaccB) * 0.5f;
    if (lane == 0) { sGA[wave] = gwA; sGB[wave] = gwB; }
    __syncthreads();

    const int tid = threadIdx.x;
    const float sA = sSA[0][tid] + sSA[1][tid] + sSA[2][tid] + sSA[3][tid];
    const float sB = sSB[0][tid] + sSB[1][tid] + sSB[2][tid] + sSB[3][tid];
    Svec[((size_t)t0 * NSLICE + slice) * D + tid] = sA;
    Svec[((size_t)t1 * NSLICE + slice) * D + tid] = sB;
    if (tid == 0) {
        gpart[t0 * NSLICE + slice] = sGA[0] + sGA[1] + sGA[2] + sGA[3];
        gpart[t1 * NSLICE + slice] = sGB[0] + sGB[1] + sGB[2] + sGB[3];
    }
}

// K2: 96 blocks x 4 targets. Combine the 8 S-slices per t, form
// loss_t = ||S_t||^2 - 2*sum_g ||S_g||^2, then one fixed-point integer
// atomicAdd per block (exact, order-independent -> deterministic).
// Last-arriving block (integer arrival counter) writes the scalar output.
__global__ __launch_bounds__(256) void k2_combine(
        const float* __restrict__ Svec, const float* __restrict__ gpart,
        unsigned long long* __restrict__ llsum, unsigned* __restrict__ cnt,
        float* __restrict__ out) {
    const int tid = threadIdx.x, wave = tid >> 6, lane = tid & 63;
    __shared__ float sR[K2_TPB][4];

#pragma unroll
    for (int tt = 0; tt < K2_TPB; ++tt) {
        const int t = blockIdx.x * K2_TPB + tt;
        const float* base = Svec + (size_t)t * NSLICE * D;
        float S = base[0*D + tid] + base[1*D + tid] + base[2*D + tid] + base[3*D + tid]
                + base[4*D + tid] + base[5*D + tid] + base[6*D + tid] + base[7*D + tid];
        const float v = wave_sum64(S * S);
        if (lane == 0) sR[tt][wave] = v;
    }
    __syncthreads();

    if (tid == 0) {
        double tot = 0.0;
#pragma unroll
        for (int tt = 0; tt < K2_TPB; ++tt) {
            const int t = blockIdx.x * K2_TPB + tt;
            const float ls = sR[tt][0] + sR[tt][1] + sR[tt][2] + sR[tt][3];
            float g = 0.f;
#pragma unroll
            for (int s = 0; s < NSLICE; ++s) g += gpart[t * NSLICE + s];
            tot += (double)(ls - 2.f * g);
        }
        const long long ll = llrint(tot * 1048576.0);   // 2^20 fixed point
        atomicAdd(llsum, (unsigned long long)ll);
        __threadfence();                                 // order sum before count
        const unsigned old = atomicAdd(cnt, 1u);
        if (old == K2_BLOCKS - 1) {                      // all sums have landed
            const unsigned long long sv = atomicAdd(llsum, 0ull);  // coherent read
            const double total = (double)(long long)sv / 1048576.0;
            out[0] = (float)(total / ((double)NS * (double)NS * (double)NT));
        }
    }
}

extern "C" void kernel_launch(void* const* d_in, const int* in_sizes, int n_in,
                              void* d_out, int out_size, void* d_ws, size_t ws_size,
                              hipStream_t stream) {
    const float* src  = (const float*)d_in[0];   // src_feats  [384, 256] f32
    const float* trgt = (const float*)d_in[1];   // trgt_feats [384, 256] f32

    float* Svec  = (float*)d_ws;                             // [384*8*256] f32 (3 MB)
    float* gpart = Svec + (size_t)NT * NSLICE * D;           // [384*8] f32
    unsigned long long* llsum =
        (unsigned long long*)(gpart + NT * NSLICE);          // 8B aligned (offset 3158016)
    unsigned* cnt = (unsigned*)(llsum + 1);
    float* out = (float*)d_out;

    k1_slices<<<K1_BLOCKS, 256, 0, stream>>>(src, trgt, Svec, gpart, llsum, cnt);
    k2_combine<<<K2_BLOCKS, 256, 0, stream>>>(Svec, gpart, llsum, cnt, out);
}